// Round 6
// baseline (588.701 us; speedup 1.0000x reference)
//
#include <hip/hip_runtime.h>

typedef unsigned short ushort_t;
typedef unsigned char u8;
typedef short bf16x8 __attribute__((ext_vector_type(8)));
typedef float f32x4 __attribute__((ext_vector_type(4)));

#define T_DIM 4
#define B_DIM 32
#define C_DIM 512
#define N_DIM 256

__device__ __forceinline__ float bf2f(ushort_t u) {
  union { unsigned int i; float f; } x;
  x.i = ((unsigned int)u) << 16;
  return x.f;
}
__device__ __forceinline__ ushort_t f2bf(float f) {
  unsigned int u = __float_as_uint(f);
  u = (u + 0x7FFFu + ((u >> 16) & 1u)) >> 16;
  return (ushort_t)u;
}
// CK-style barrier: LDS visibility only, never drains vmcnt (avoids the
// m97 "vmcnt(0) before s_barrier" structural stall).
__device__ __forceinline__ void sync_lds() {
  asm volatile("s_waitcnt lgkmcnt(0)\ns_barrier" ::: "memory");
}

// ---------------------------------------------------------------------------
// K0: split fp32 weights into 3 bf16 planes (hi, mid, lo). W ~= hi+mid+lo.
// ---------------------------------------------------------------------------
__global__ __launch_bounds__(256) void k0_split(
    const float* __restrict__ Wq, const float* __restrict__ Wk,
    const float* __restrict__ Wv, const float* __restrict__ Wp,
    ushort_t* __restrict__ Sqkv, ushort_t* __restrict__ Sp)
{
  int gid = blockIdx.x * 256 + threadIdx.x;
  int w = gid >> 15;
  int off = (gid & 32767) * 8;
  const float* src = (w == 0) ? Wq : ((w == 1) ? Wk : ((w == 2) ? Wv : Wp));
  ushort_t* dst = (w < 3) ? (Sqkv + (size_t)w * 3 * 262144) : Sp;
  float wv[8];
  *(float4*)&wv[0] = *(const float4*)(src + off);
  *(float4*)&wv[4] = *(const float4*)(src + off + 4);
  ushort_t hi[8], mi[8], lo[8];
#pragma unroll
  for (int i = 0; i < 8; i++) {
    float f = wv[i];
    ushort_t h = f2bf(f);  float r  = f - bf2f(h);
    ushort_t m = f2bf(r);  float r2 = r - bf2f(m);
    ushort_t l = f2bf(r2);
    hi[i] = h; mi[i] = m; lo[i] = l;
  }
  *(uint4*)(dst + off)              = *(uint4*)&hi[0];
  *(uint4*)(dst + 262144 + off)     = *(uint4*)&mi[0];
  *(uint4*)(dst + 2 * 262144 + off) = *(uint4*)&lo[0];
}

// ---------------------------------------------------------------------------
// K1: shortcut LIF on x [T,B,C,N] (fp32) -> spikes transposed xsT8 [T,B,N,C] u8
// ---------------------------------------------------------------------------
__global__ __launch_bounds__(256) void k1_shortcut_lif(
    const float* __restrict__ x, u8* __restrict__ xsT8)
{
  const int n0 = blockIdx.x * 64;
  const int c0 = blockIdx.y * 64;
  const int b  = blockIdx.z;
  __shared__ u8 sm[64][80];
  const int tid = threadIdx.x;
  const int r  = tid >> 2;
  const int j0 = (tid & 3) * 16;
  float v[16];
#pragma unroll
  for (int i = 0; i < 16; i++) v[i] = 0.f;
  for (int t = 0; t < T_DIM; t++) {
    const float* xp = x + ((((size_t)t * B_DIM + b) * C_DIM) + c0 + r) * N_DIM + n0 + j0;
    float xv[16];
    *(float4*)&xv[0]  = *(const float4*)xp;
    *(float4*)&xv[4]  = *(const float4*)(xp + 4);
    *(float4*)&xv[8]  = *(const float4*)(xp + 8);
    *(float4*)&xv[12] = *(const float4*)(xp + 12);
    __syncthreads();
#pragma unroll
    for (int i = 0; i < 16; i++) {
      float nv = v[i] + (xv[i] - v[i]) * 0.5f;
      bool s = (nv >= 1.0f);
      v[i] = s ? 0.f : nv;
      sm[j0 + i][r] = s ? (u8)1 : (u8)0;
    }
    __syncthreads();
    union { uint4 u; u8 b[16]; } ov;
#pragma unroll
    for (int i = 0; i < 16; i++) ov.b[i] = sm[r][j0 + i];
    u8* op = xsT8 + ((((size_t)t * B_DIM + b) * N_DIM) + n0 + r) * C_DIM + c0 + j0;
    *(uint4*)op = ov.u;
  }
}

// ---------------------------------------------------------------------------
// K2: QKV conv1x1 + BN + LIF. 512 threads, 64m x 128n, depth-2 register
// pipeline: LOAD(s+2); WRITE(s+1 from regs loaded at s-1); MFMA(s); sync_lds.
// ---------------------------------------------------------------------------
__global__ __launch_bounds__(512, 4) void k2_qkv(
    const u8* __restrict__ xsT8, const ushort_t* __restrict__ Sqkv,
    const float* __restrict__ qsc, const float* __restrict__ qbi,
    const float* __restrict__ ksc, const float* __restrict__ kbi,
    const float* __restrict__ vsc, const float* __restrict__ vbi,
    u8* __restrict__ qs8, u8* __restrict__ ks8, float* __restrict__ vout)
{
  const int nt = blockIdx.x;          // 0..1
  const int mt = blockIdx.y;          // 0..23
  const int b  = blockIdx.z;          // 0..31
  const int branch = mt >> 3;
  const int mloc = (mt & 7) * 64;
  const ushort_t* Ws = Sqkv + (size_t)branch * 3 * 262144;
  const float* scp = (branch == 0) ? qsc : ((branch == 1) ? ksc : vsc);
  const float* bip = (branch == 0) ? qbi : ((branch == 1) ? kbi : vbi);

  __shared__ ushort_t As3[2][3][64][32];
  __shared__ ushort_t Bs[2][128][32];

  const int tid  = threadIdx.x;
  const int lane = tid & 63;
  const int wave = tid >> 6;
  const int wrow = (wave >> 1) * 16;
  const int wcol = (wave & 1) * 64;
  const int frow = lane & 15;
  const int fsl  = lane >> 4;

  const u8* Bb0 = xsT8 + ((size_t)b * N_DIM + nt * 128) * C_DIM;

  const int ap0 = tid >> 8, ar0 = (tid & 255) >> 2, asl0 = tid & 3;
  const int ach1 = tid + 512;
  const int ap1 = ach1 >> 8, ar1 = (ach1 & 255) >> 2, asl1 = ach1 & 3;
  const int brow = tid >> 1, bsl0 = (tid & 1) * 2;

  uint4 pa0_0, pa1_0, pb_0;   // set 0
  uint4 pa0_1, pa1_1, pb_1;   // set 1

#define K2_LOAD(s_, A0, A1, PB) { int t_ = (s_) >> 4; int kb_ = ((s_) & 15) * 32;          \
    A0 = *(const uint4*)(Ws + (size_t)ap0 * 262144 + (size_t)(mloc + ar0) * 512 + kb_ + asl0 * 8); \
    if (tid < 256) {                                                                        \
      A1 = *(const uint4*)(Ws + (size_t)ap1 * 262144 + (size_t)(mloc + ar1) * 512 + kb_ + asl1 * 8); \
      PB = *(const uint4*)(Bb0 + (size_t)t_ * B_DIM * N_DIM * C_DIM + (size_t)brow * 512 + kb_ + bsl0 * 8); \
    } }

#define K2_WRITE(buf_, A0, A1, PB) {                                                       \
    *(uint4*)&As3[buf_][ap0][ar0][(asl0 ^ ((ar0 >> 1) & 3)) * 8] = A0;                     \
    if (tid < 256) {                                                                        \
      *(uint4*)&As3[buf_][ap1][ar1][(asl1 ^ ((ar1 >> 1) & 3)) * 8] = A1;                   \
      union { uint4 u; u8 bb[16]; } rw_; rw_.u = PB;                                       \
      ushort_t tmp_[16];                                                                   \
      _Pragma("unroll") for (int z_ = 0; z_ < 16; z_++) tmp_[z_] = rw_.bb[z_] ? (ushort_t)0x3F80u : (ushort_t)0u; \
      int sw_ = (brow >> 1) & 3;                                                           \
      *(uint4*)&Bs[buf_][brow][((bsl0) ^ sw_) * 8]     = *(uint4*)&tmp_[0];                \
      *(uint4*)&Bs[buf_][brow][((bsl0 + 1) ^ sw_) * 8] = *(uint4*)&tmp_[8];                \
    } }

#define K2_MFMA(buf_) {                                                                    \
    bf16x8 bfr_[4];                                                                        \
    _Pragma("unroll") for (int j_ = 0; j_ < 4; j_++) {                                     \
      int row_ = wcol + j_ * 16 + frow;                                                    \
      bfr_[j_] = *(const bf16x8*)&Bs[buf_][row_][(fsl ^ ((row_ >> 1) & 3)) * 8]; }         \
    int arow_ = wrow + frow; int asw_ = (fsl ^ ((arow_ >> 1) & 3)) * 8;                    \
    _Pragma("unroll") for (int p_ = 0; p_ < 3; p_++) {                                     \
      bf16x8 af_ = *(const bf16x8*)&As3[buf_][p_][arow_][asw_];                            \
      _Pragma("unroll") for (int j_ = 0; j_ < 4; j_++)                                     \
        acc[j_] = __builtin_amdgcn_mfma_f32_16x16x32_bf16(af_, bfr_[j_], acc[j_], 0, 0, 0); } }

#define K2_EPI(t_) {                                                                       \
    const size_t tb_ = (size_t)(t_) * B_DIM + b;                                           \
    if (branch < 2) {                                                                      \
      u8* dst_ = (branch == 0) ? qs8 : ks8;                                                \
      _Pragma("unroll") for (int r_ = 0; r_ < 4; r_++) {                                   \
        int c_ = mloc + wrow + crow0 + r_;                                                 \
        _Pragma("unroll") for (int j_ = 0; j_ < 4; j_++) {                                 \
          int n_ = nt * 128 + wcol + j_ * 16 + cn;                                         \
          float y_ = acc[j_][r_] * sc4[r_] + bi4[r_];                                      \
          int vi_ = j_ * 4 + r_;                                                           \
          float v_ = vst[vi_];                                                             \
          v_ = v_ + (y_ - v_) * 0.5f;                                                      \
          bool sp_ = (v_ >= 1.0f);                                                         \
          vst[vi_] = sp_ ? 0.f : v_;                                                       \
          dst_[(tb_ * C_DIM + c_) * N_DIM + n_] = sp_ ? (u8)1 : (u8)0;                     \
        } }                                                                                \
    } else {                                                                               \
      const int hv_ = mloc >> 6;                                                           \
      const int d0_ = wrow + crow0;                                                        \
      _Pragma("unroll") for (int j_ = 0; j_ < 4; j_++) {                                   \
        int n_ = nt * 128 + wcol + j_ * 16 + cn;                                           \
        float ov_[4];                                                                      \
        _Pragma("unroll") for (int r_ = 0; r_ < 4; r_++) {                                 \
          float y_ = acc[j_][r_] * sc4[r_] + bi4[r_];                                      \
          int vi_ = j_ * 4 + r_;                                                           \
          float v_ = vst[vi_];                                                             \
          v_ = v_ + (y_ - v_) * 0.5f;                                                      \
          bool sp_ = (v_ >= 1.0f);                                                         \
          vst[vi_] = sp_ ? 0.f : v_;                                                       \
          ov_[r_] = sp_ ? 1.0f : 0.0f;                                                     \
        }                                                                                  \
        float4 o_; o_.x = ov_[0]; o_.y = ov_[1]; o_.z = ov_[2]; o_.w = ov_[3];             \
        *(float4*)(vout + ((tb_ * 8 + hv_) * N_DIM + n_) * 64 + d0_) = o_;                 \
      } }                                                                                  \
    _Pragma("unroll") for (int i_ = 0; i_ < 4; i_++) acc[i_] = (f32x4){0.f, 0.f, 0.f, 0.f}; }

  f32x4 acc[4];
  float vst[16];
#pragma unroll
  for (int i = 0; i < 16; i++) vst[i] = 0.f;
#pragma unroll
  for (int i = 0; i < 4; i++) acc[i] = (f32x4){0.f, 0.f, 0.f, 0.f};

  const int crow0 = (lane >> 4) * 4;
  const int cn    = lane & 15;
  float sc4[4], bi4[4];
#pragma unroll
  for (int r = 0; r < 4; r++) {
    int c = mloc + wrow + crow0 + r;
    sc4[r] = scp[c]; bi4[r] = bip[c];
  }

  // prologue: buf0 <- step0 ; set1 <- step1 (in flight)
  K2_LOAD(0, pa0_0, pa1_0, pb_0);
  K2_WRITE(0, pa0_0, pa1_0, pb_0);
  K2_LOAD(1, pa0_1, pa1_1, pb_1);
  __syncthreads();

  for (int ss = 0; ss < 32; ss++) {
    const int s0 = ss * 2;
    // even step s0: compute buf0
    if (s0 + 2 < 64) K2_LOAD(s0 + 2, pa0_0, pa1_0, pb_0);
    K2_WRITE(1, pa0_1, pa1_1, pb_1);       // data for step s0+1
    K2_MFMA(0);
    sync_lds();
    // odd step s0+1: compute buf1
    if (s0 + 3 < 64) K2_LOAD(s0 + 3, pa0_1, pa1_1, pb_1);
    if (s0 + 2 < 64) K2_WRITE(0, pa0_0, pa1_0, pb_0);   // data for step s0+2
    K2_MFMA(1);
    if (((s0 + 1) & 15) == 15) K2_EPI((s0 + 1) >> 4);
    sync_lds();
  }
#undef K2_LOAD
#undef K2_WRITE
#undef K2_MFMA
#undef K2_EPI
}

// ---------------------------------------------------------------------------
// K3: attn_part[t][b][h][d][e] = (1/16) * sum_n k[d,n] * v[n,e]  (per-t slice)
// Exact fp32 (integer sums * 1/16). k4 sums the two slices of each chunk.
// ---------------------------------------------------------------------------
__global__ __launch_bounds__(256) void k3_attn(
    const u8* __restrict__ ks8, const float* __restrict__ vsp,
    float* __restrict__ attn_part)
{
  const int h = blockIdx.x;
  const int b = blockIdx.y;
  const int t = blockIdx.z;   // 0..3
  __shared__ u8 KtT[64][80];
  __shared__ u8 Vt[64][80];
  const int tid = threadIdx.x;
  const int d0 = (tid >> 4) * 4;
  const int e0 = (tid & 15) * 4;
  float a[16];
#pragma unroll
  for (int i = 0; i < 16; i++) a[i] = 0.f;

  for (int n0 = 0; n0 < 256; n0 += 64) {
    __syncthreads();
    {
      int d  = tid >> 2;
      int s0 = (tid & 3) * 16;
      union { uint4 u; u8 bvec[16]; } kb;
      kb.u = *(const uint4*)(ks8 + ((((size_t)t * B_DIM + b) * C_DIM) + h * 64 + d) * N_DIM + n0 + s0);
#pragma unroll
      for (int i = 0; i < 16; i++) KtT[s0 + i][d] = kb.bvec[i];
    }
    {
      const float* vb = vsp + ((((size_t)t * B_DIM + b) * 8 + h) * N_DIM + n0) * 64;
#pragma unroll
      for (int u = 0; u < 4; u++) {
        int chunk = tid + u * 256;
        int row = chunk >> 4;
        int eo  = (chunk & 15) * 4;
        float4 v4 = *(const float4*)(vb + (size_t)row * 64 + eo);
        Vt[row][eo + 0] = (u8)(v4.x != 0.f);
        Vt[row][eo + 1] = (u8)(v4.y != 0.f);
        Vt[row][eo + 2] = (u8)(v4.z != 0.f);
        Vt[row][eo + 3] = (u8)(v4.w != 0.f);
      }
    }
    __syncthreads();
    for (int s = 0; s < 64; s++) {
      uchar4 kb = *(const uchar4*)&KtT[s][d0];
      float kv[4] = { (float)kb.x, (float)kb.y, (float)kb.z, (float)kb.w };
      uchar4 vr = *(const uchar4*)&Vt[s][e0];
      float vv[4] = { (float)vr.x, (float)vr.y, (float)vr.z, (float)vr.w };
#pragma unroll
      for (int i = 0; i < 4; i++)
#pragma unroll
        for (int j = 0; j < 4; j++) a[i * 4 + j] += kv[i] * vv[j];
    }
  }
  float* ap = attn_part + (((size_t)t * B_DIM + b) * 8 + h) * 4096 + d0 * 64 + e0;
#pragma unroll
  for (int i = 0; i < 4; i++)
#pragma unroll
    for (int j = 0; j < 4; j++)
      ap[i * 64 + j] = a[i * 4 + j] * 0.0625f;
}

// ---------------------------------------------------------------------------
// K4: out[e,n] = sum_d (part[2ch]+part[2ch+1])[d,e] * q[d,n], LIF(0.5)
// -> x2sT8[t,b,n,c] u8.  grid z = n-chunk.
// ---------------------------------------------------------------------------
__global__ __launch_bounds__(256) void k4_out_lif(
    const u8* __restrict__ qs8, const float* __restrict__ attn_part,
    u8* __restrict__ x2sT8)
{
  const int h  = blockIdx.x;
  const int b  = blockIdx.y;
  const int nc = blockIdx.z;   // 0..3
  __shared__ float At[64][68];
  __shared__ u8 Qt[64][80];
  const int tid = threadIdx.x;
  const int e0 = (tid >> 4) * 4;
  const int n0 = (tid & 15) * 4;
  float vst[16];
#pragma unroll
  for (int i = 0; i < 16; i++) vst[i] = 0.f;

  for (int t = 0; t < T_DIM; t++) {
    __syncthreads();
    if ((t & 1) == 0) {
      const float* p0 = attn_part + (((size_t)t * B_DIM + b) * 8 + h) * 4096;
      const float* p1 = p0 + (size_t)B_DIM * 8 * 4096;
      int dr = tid >> 2;
      int co = (tid & 3) * 16;
#pragma unroll
      for (int u = 0; u < 4; u++) {
        float4 a0 = *(const float4*)(p0 + dr * 64 + co + u * 4);
        float4 a1 = *(const float4*)(p1 + dr * 64 + co + u * 4);
        float4 sum; sum.x = a0.x + a1.x; sum.y = a0.y + a1.y;
        sum.z = a0.z + a1.z; sum.w = a0.w + a1.w;
        *(float4*)&At[dr][co + u * 4] = sum;
      }
    }
    {
      int d  = tid >> 2;
      int so = (tid & 3) * 16;
      *(uint4*)&Qt[d][so] =
        *(const uint4*)(qs8 + ((((size_t)t * B_DIM + b) * C_DIM) + h * 64 + d) * N_DIM + nc * 64 + so);
    }
    __syncthreads();
    float acc[16];
#pragma unroll
    for (int i = 0; i < 16; i++) acc[i] = 0.f;
    for (int d = 0; d < 64; d++) {
      float4 av = *(const float4*)&At[d][e0];
      float avv[4] = { av.x, av.y, av.z, av.w };
      uchar4 qr = *(const uchar4*)&Qt[d][n0];
      float qv[4] = { (float)qr.x, (float)qr.y, (float)qr.z, (float)qr.w };
#pragma unroll
      for (int i = 0; i < 4; i++)
#pragma unroll
        for (int j = 0; j < 4; j++) acc[i * 4 + j] += avv[i] * qv[j];
    }
#pragma unroll
    for (int j = 0; j < 4; j++) {
      u8 sv[4];
#pragma unroll
      for (int i = 0; i < 4; i++) {
        int vi = i * 4 + j;
        float y = acc[i * 4 + j];
        float nv = vst[vi] + (y - vst[vi]) * 0.5f;
        bool s = (nv >= 0.5f);
        vst[vi] = s ? 0.f : nv;
        sv[i] = s ? (u8)1 : (u8)0;
      }
      int n = nc * 64 + n0 + j;
      u8* op = x2sT8 + ((((size_t)t * B_DIM + b) * N_DIM) + n) * C_DIM + h * 64 + e0;
      *(uchar4*)op = make_uchar4(sv[0], sv[1], sv[2], sv[3]);
    }
  }
}

// ---------------------------------------------------------------------------
// K5: proj conv1x1 (+bp)*scale+bias + residual -> out0 fp32. Same depth-2
// pipeline engine as K2. 16 k-steps.
// ---------------------------------------------------------------------------
__global__ __launch_bounds__(512, 4) void k5_proj(
    const u8* __restrict__ x2sT8, const ushort_t* __restrict__ Sp,
    const float* __restrict__ bp, const float* __restrict__ psc,
    const float* __restrict__ pbi,
    const float* __restrict__ x, float* __restrict__ out0)
{
  const int nt = blockIdx.x;   // 0..1
  const int mt = blockIdx.y;   // 0..7
  const int tb = blockIdx.z;   // 0..127
  const int mloc = mt * 64;

  __shared__ ushort_t As3[2][3][64][32];
  __shared__ ushort_t Bs[2][128][32];

  const int tid  = threadIdx.x;
  const int lane = tid & 63;
  const int wave = tid >> 6;
  const int wrow = (wave >> 1) * 16;
  const int wcol = (wave & 1) * 64;
  const int frow = lane & 15;
  const int fsl  = lane >> 4;

  const u8* Bb = x2sT8 + ((size_t)tb * N_DIM + nt * 128) * C_DIM;

  const int ap0 = tid >> 8, ar0 = (tid & 255) >> 2, asl0 = tid & 3;
  const int ach1 = tid + 512;
  const int ap1 = ach1 >> 8, ar1 = (ach1 & 255) >> 2, asl1 = ach1 & 3;
  const int brow = tid >> 1, bsl0 = (tid & 1) * 2;

  uint4 pa0_0, pa1_0, pb_0;
  uint4 pa0_1, pa1_1, pb_1;

#define K5_LOAD(s_, A0, A1, PB) { int kb_ = (s_) * 32;                                     \
    A0 = *(const uint4*)(Sp + (size_t)ap0 * 262144 + (size_t)(mloc + ar0) * 512 + kb_ + asl0 * 8); \
    if (tid < 256) {                                                                        \
      A1 = *(const uint4*)(Sp + (size_t)ap1 * 262144 + (size_t)(mloc + ar1) * 512 + kb_ + asl1 * 8); \
      PB = *(const uint4*)(Bb + (size_t)brow * 512 + kb_ + bsl0 * 8);                      \
    } }

#define K5_WRITE(buf_, A0, A1, PB) {                                                       \
    *(uint4*)&As3[buf_][ap0][ar0][(asl0 ^ ((ar0 >> 1) & 3)) * 8] = A0;                     \
    if (tid < 256) {                                                                        \
      *(uint4*)&As3[buf_][ap1][ar1][(asl1 ^ ((ar1 >> 1) & 3)) * 8] = A1;                   \
      union { uint4 u; u8 bb[16]; } rw_; rw_.u = PB;                                       \
      ushort_t tmp_[16];                                                                   \
      _Pragma("unroll") for (int z_ = 0; z_ < 16; z_++) tmp_[z_] = rw_.bb[z_] ? (ushort_t)0x3F80u : (ushort_t)0u; \
      int sw_ = (brow >> 1) & 3;                                                           \
      *(uint4*)&Bs[buf_][brow][((bsl0) ^ sw_) * 8]     = *(uint4*)&tmp_[0];                \
      *(uint4*)&Bs[buf_][brow][((bsl0 + 1) ^ sw_) * 8] = *(uint4*)&tmp_[8];                \
    } }

#define K5_MFMA(buf_) {                                                                    \
    bf16x8 bfr_[4];                                                                        \
    _Pragma("unroll") for (int j_ = 0; j_ < 4; j_++) {                                     \
      int row_ = wcol + j_ * 16 + frow;                                                    \
      bfr_[j_] = *(const bf16x8*)&Bs[buf_][row_][(fsl ^ ((row_ >> 1) & 3)) * 8]; }         \
    int arow_ = wrow + frow; int asw_ = (fsl ^ ((arow_ >> 1) & 3)) * 8;                    \
    _Pragma("unroll") for (int p_ = 0; p_ < 3; p_++) {                                     \
      bf16x8 af_ = *(const bf16x8*)&As3[buf_][p_][arow_][asw_];                            \
      _Pragma("unroll") for (int j_ = 0; j_ < 4; j_++)                                     \
        acc[j_] = __builtin_amdgcn_mfma_f32_16x16x32_bf16(af_, bfr_[j_], acc[j_], 0, 0, 0); } }

  f32x4 acc[4];
#pragma unroll
  for (int i = 0; i < 4; i++) acc[i] = (f32x4){0.f, 0.f, 0.f, 0.f};

  K5_LOAD(0, pa0_0, pa1_0, pb_0);
  K5_WRITE(0, pa0_0, pa1_0, pb_0);
  K5_LOAD(1, pa0_1, pa1_1, pb_1);
  __syncthreads();

  for (int ss = 0; ss < 8; ss++) {
    const int s0 = ss * 2;
    if (s0 + 2 < 16) K5_LOAD(s0 + 2, pa0_0, pa1_0, pb_0);
    K5_WRITE(1, pa0_1, pa1_1, pb_1);
    K5_MFMA(0);
    sync_lds();
    if (s0 + 3 < 16) K5_LOAD(s0 + 3, pa0_1, pa1_1, pb_1);
    if (s0 + 2 < 16) K5_WRITE(0, pa0_0, pa1_0, pb_0);
    K5_MFMA(1);
    sync_lds();
  }

  const int crow0 = (lane >> 4) * 4;
  const int cn    = lane & 15;
#pragma unroll
  for (int r = 0; r < 4; r++) {
    int c = mloc + wrow + crow0 + r;
    float scf = psc[c];
    float bif = pbi[c];
    float bpf = bp[c];
#pragma unroll
    for (int j = 0; j < 4; j++) {
      int n = nt * 128 + wcol + j * 16 + cn;
      size_t idx = ((size_t)tb * C_DIM + c) * N_DIM + n;
      out0[idx] = (acc[j][r] + bpf) * scf + bif + x[idx];
    }
  }
#undef K5_LOAD
#undef K5_WRITE
#undef K5_MFMA
}

// ---------------------------------------------------------------------------
// fp32 problem. d_out = 33,554,432 floats: out0 [0,16.7M), out1 [16.7M,33.5M).
// Scratch in out0 byte region (dead until K5 overwrites it):
//   o0+0    xsT8 16MiB [K1->K2]; REUSED as attn_part 16MiB [K3->K4] (exact fit)
//   o0+16M  qs8 16MiB [K2->K4] ; o0+32M ks8 16MiB [K2->K3]
//   o0+48M  Sqkv split 4.5MB [K0->K2]
// d_ws: x2sT8 16MiB [K4->K5]; +16M Sp split 1.5MB [K0->K5].
// ---------------------------------------------------------------------------
extern "C" void kernel_launch(void* const* d_in, const int* in_sizes, int n_in,
                              void* d_out, int out_size, void* d_ws, size_t ws_size,
                              hipStream_t stream) {
  const float* x   = (const float*)d_in[0];
  const float* Wq  = (const float*)d_in[1];
  const float* qsc = (const float*)d_in[2];
  const float* qbi = (const float*)d_in[3];
  const float* Wk  = (const float*)d_in[4];
  const float* ksc = (const float*)d_in[5];
  const float* kbi = (const float*)d_in[6];
  const float* Wv  = (const float*)d_in[7];
  const float* vsc = (const float*)d_in[8];
  const float* vbi = (const float*)d_in[9];
  const float* Wp  = (const float*)d_in[10];
  const float* bp  = (const float*)d_in[11];
  const float* psc = (const float*)d_in[12];
  const float* pbi = (const float*)d_in[13];

  float* out0 = (float*)d_out;
  float* out1 = out0 + 16777216;

  const size_t M16 = 16u * 1024u * 1024u;
  char* o0 = (char*)d_out;
  char* ws = (char*)d_ws;

  u8*       xsT8  = (u8*)(o0);
  u8*       qs8   = (u8*)(o0 + M16);
  u8*       ks8   = (u8*)(o0 + 2 * M16);
  ushort_t* Sqkv  = (ushort_t*)(o0 + 3 * M16);
  float*    attn_part = (float*)(o0);           // aliases xsT8 (dead after K2)
  u8*       x2sT8 = (u8*)(ws);
  ushort_t* Sp    = (ushort_t*)(ws + M16);

  hipLaunchKernelGGL(k0_split,        dim3(512),        dim3(256), 0, stream,
                     Wq, Wk, Wv, Wp, Sqkv, Sp);
  hipLaunchKernelGGL(k1_shortcut_lif, dim3(4, 8, 32),   dim3(256), 0, stream, x, xsT8);
  hipLaunchKernelGGL(k2_qkv,          dim3(2, 24, 32),  dim3(512), 0, stream,
                     xsT8, Sqkv, qsc, qbi, ksc, kbi, vsc, vbi, qs8, ks8, out1);
  hipLaunchKernelGGL(k3_attn,         dim3(8, 32, 4),   dim3(256), 0, stream, ks8, out1, attn_part);
  hipLaunchKernelGGL(k4_out_lif,      dim3(8, 32, 4),   dim3(256), 0, stream, qs8, attn_part, x2sT8);
  hipLaunchKernelGGL(k5_proj,         dim3(2, 8, 128),  dim3(512), 0, stream,
                     x2sT8, Sp, bp, psc, pbi, x, out0);
}